// Round 6
// baseline (147.496 us; speedup 1.0000x reference)
//
#include <hip/hip_runtime.h>

// Reverb via FFT overlap-save cross-correlation. R6: 2-pass radix-1024.
// L = 2^20 = 1024*1024. Each pass does a full local 1024-pt FFT per
// 64-thread group (sub-stages radix 16,16,4 with 2 padded LDS exchanges).
// Pass-1 writes TRANSPOSED [k2*1024 + n1]; spectra stored line-major, which
// makes the inverse pass-1 read CONTIGUOUS (digit-swap cancels the gather).
// Spectral multiply fused into fwd pass 2 via mirror-line pairing
// (k2 <-> 1024-k2; 0 and 512 self-mirror), H computed concurrently in-block.
// 5 kernels, ~161 MB total traffic, all major streams >=32B granule.

#define L_FFT (1 << 20)
#define AREA 1088   // padded 1024-elem float2 transform area (LP(1023)=1086)

// padded LDS index: +1 float2 every 16 -> lane-varying bank spread (R5 fix)
__device__ __forceinline__ int LP(int i) { return i + (i >> 4); }

__device__ __forceinline__ float2 cmul(float2 a, float2 b) {
    return make_float2(a.x * b.x - a.y * b.y, a.x * b.y + a.y * b.x);
}

__device__ __forceinline__ void rad4(float2 a, float2 b, float2 c, float2 d,
                                     float2& o0, float2& o1, float2& o2, float2& o3) {
    float2 apc = make_float2(a.x + c.x, a.y + c.y);
    float2 amc = make_float2(a.x - c.x, a.y - c.y);
    float2 bpd = make_float2(b.x + d.x, b.y + d.y);
    float2 bmd = make_float2(b.x - d.x, b.y - d.y);
    o0 = make_float2(apc.x + bpd.x, apc.y + bpd.y);
    o2 = make_float2(apc.x - bpd.x, apc.y - bpd.y);
    o1 = make_float2(amc.x + bmd.y, amc.y - bmd.x);
    o3 = make_float2(amc.x - bmd.y, amc.y + bmd.x);
}

// 16-pt DFT, natural order in/out (bench-verified R2-R5).
__device__ __forceinline__ void dft16(float2 x[16]) {
    float2 tt[16];
    rad4(x[0], x[4], x[8],  x[12], tt[0],  tt[1],  tt[2],  tt[3]);
    rad4(x[1], x[5], x[9],  x[13], tt[4],  tt[5],  tt[6],  tt[7]);
    rad4(x[2], x[6], x[10], x[14], tt[8],  tt[9],  tt[10], tt[11]);
    rad4(x[3], x[7], x[11], x[15], tt[12], tt[13], tt[14], tt[15]);
    const float C1 = 0.92387953251128675613f, S1 = 0.38268343236508977173f;
    const float C2 = 0.70710678118654752440f;
    const float2 W1 = make_float2( C1, -S1);
    const float2 W2 = make_float2( C2, -C2);
    const float2 W3 = make_float2( S1, -C1);
    const float2 W6 = make_float2(-C2, -C2);
    const float2 W9 = make_float2(-C1,  S1);
    tt[5]  = cmul(tt[5],  W1);
    tt[6]  = cmul(tt[6],  W2);
    tt[7]  = cmul(tt[7],  W3);
    tt[9]  = cmul(tt[9],  W2);
    tt[10] = make_float2(tt[10].y, -tt[10].x);
    tt[11] = cmul(tt[11], W6);
    tt[13] = cmul(tt[13], W3);
    tt[14] = cmul(tt[14], W6);
    tt[15] = cmul(tt[15], W9);
    rad4(tt[0], tt[4], tt[8],  tt[12], x[0], x[4], x[8],  x[12]);
    rad4(tt[1], tt[5], tt[9],  tt[13], x[1], x[5], x[9],  x[13]);
    rad4(tt[2], tt[6], tt[10], tt[14], x[2], x[6], x[10], x[14]);
    rad4(tt[3], tt[7], tt[11], tt[15], x[3], x[7], x[11], x[15]);
}

// Local 1024-pt DFT for one transform across 64 threads (t = lane in group).
// Entry: x[q'] = y[t + 64*q'].  Exit: bins b[4*c + r4] = Y[t + 64*c + 256*r4].
// Sub-stages are verbatim Stockham instances: (R=16,J=1), (R=16,J=16),
// (R=4,J=256, trivial twiddles). `area` = this transform's padded LDS region.
// Caller may have pending LDS reads; first barrier here covers them.
// No trailing barrier — caller must sync before reusing LDS.
__device__ void fft1024_local(float2 x[16], float2 b[16], int t, float2* area) {
    float sa, ca;
    // sub-stage A: radix-16, J=1: np=t, Ln=1024; write z[16t + r1]
    dft16(x);
    __sincosf(-6.28318530717958647692f * (float)t * (1.0f / 1024.0f), &sa, &ca);
    {
        float2 w1 = make_float2(ca, sa), w = w1;
#pragma unroll
        for (int r1 = 1; r1 < 16; ++r1) { x[r1] = cmul(x[r1], w); w = cmul(w, w1); }
    }
    __syncthreads();
#pragma unroll
    for (int r1 = 0; r1 < 16; ++r1) area[LP(16 * t + r1)] = x[r1];
    __syncthreads();
    // sub-stage B: radix-16, J=16: read z[t + 64q'], np=t>>4, Ln=64,
    // write u[256*(t>>4) + (t&15) + 16*r2]
#pragma unroll
    for (int q = 0; q < 16; ++q) x[q] = area[LP(t + 64 * q)];
    dft16(x);
    __sincosf(-6.28318530717958647692f * (float)(t >> 4) * (1.0f / 64.0f), &sa, &ca);
    {
        float2 w1 = make_float2(ca, sa), w = w1;
#pragma unroll
        for (int r2 = 1; r2 < 16; ++r2) { x[r2] = cmul(x[r2], w); w = cmul(w, w1); }
    }
    __syncthreads();
    {
        int ub = 256 * (t >> 4) + (t & 15);
#pragma unroll
        for (int r2 = 0; r2 < 16; ++r2) area[LP(ub + 16 * r2)] = x[r2];
    }
    __syncthreads();
    // sub-stage C: radix-4, J=256: read u[gC + 256q], gC = t + 64c; trivial
    // twiddles; bins r = gC + 256*r4.
#pragma unroll
    for (int c = 0; c < 4; ++c) {
        float2 y0 = area[LP(t + 64 * c)];
        float2 y1 = area[LP(t + 64 * c + 256)];
        float2 y2 = area[LP(t + 64 * c + 512)];
        float2 y3 = area[LP(t + 64 * c + 768)];
        rad4(y0, y1, y2, y3, b[4 * c], b[4 * c + 1], b[4 * c + 2], b[4 * c + 3]);
    }
}

// Apply stage twiddle w_L^{g*r}, r = t + 64c + 256r4 (3 sincos + chains).
__device__ __forceinline__ void twiddle_L(float2 b[16], int g, int t) {
    float th = -6.28318530717958647692f * (float)g * (1.0f / (float)L_FFT);
    float sa, ca;
    __sincosf(th * (float)t, &sa, &ca);
    float2 wt = make_float2(ca, sa);
    __sincosf(th * 64.0f, &sa, &ca);
    float2 c64 = make_float2(ca, sa);
    __sincosf(th * 256.0f, &sa, &ca);
    float2 c256 = make_float2(ca, sa);
    float2 wrow = wt;
#pragma unroll
    for (int r4 = 0; r4 < 4; ++r4) {
        if (r4) wrow = cmul(wrow, c256);
        float2 wc = wrow;
#pragma unroll
        for (int c = 0; c < 4; ++c) {
            if (c) wc = cmul(wc, c64);
            b[4 * c + r4] = cmul(b[4 * c + r4], wc);
        }
    }
}

// ---- K1: pack + forward pass 1. Block: 4 transforms (n1 = 4*bx+tau),
// slot = blockIdx.y (0: seg0+i*seg1, 1: seg2+i*seg3, 2: ir).
// Stages audio tiles via LDS (stride-5 float rows), writes transposed
// T[slot][r*1024 + n1] as 32B runs.
__global__ __launch_bounds__(256) void fwd1_pack(const float* __restrict__ audio,
                                                 const float* __restrict__ ir,
                                                 float2* __restrict__ T,
                                                 int N, int M, int V) {
    __shared__ __align__(16) char smem[40960];
    float* tileA = (float*)smem;            // [1024][5] floats (Re source)
    float* tileB = tileA + 5120;            // [1024][5] floats (Im source)
    float2* areas = (float2*)smem;          // 4 x AREA float2 (after barrier)
    float2* rtile = (float2*)smem;          // [1024][5] float2 retranspose

    int tid = threadIdx.x;
    int bx = blockIdx.x, slot = blockIdx.y;
    // --- stage input tile: element (row, j) = src[4bx + j + 1024*row] ---
#pragma unroll
    for (int it = 0; it < 4; ++it) {
        int row = tid + 256 * it;
        int idx = 4 * bx + 1024 * row;
        if (slot == 0) {
            float4 a0 = *(const float4*)(audio + idx);           // seg0: always valid
            tileA[row * 5 + 0] = a0.x; tileA[row * 5 + 1] = a0.y;
            tileA[row * 5 + 2] = a0.z; tileA[row * 5 + 3] = a0.w;
#pragma unroll
            for (int j = 0; j < 4; ++j)                          // seg1: valid, V%4!=0
                tileB[row * 5 + j] = audio[idx + j + V];
        } else if (slot == 1) {
#pragma unroll
            for (int j = 0; j < 4; ++j) {
                int e = idx + j;
                tileA[row * 5 + j] = (e + 2 * V < N) ? audio[e + 2 * V] : 0.f;
                tileB[row * 5 + j] = (e + 3 * V < N) ? audio[e + 3 * V] : 0.f;
            }
        } else {
#pragma unroll
            for (int j = 0; j < 4; ++j) {
                int e = idx + j;
                tileA[row * 5 + j] = (e < M) ? ir[e] : 0.f;
            }
        }
    }
    __syncthreads();
    // --- local FFT per transform ---
    int tau = tid >> 6, t = tid & 63;
    float2 x[16];
#pragma unroll
    for (int q = 0; q < 16; ++q) {
        int e = t + 64 * q;
        float re = tileA[e * 5 + tau];
        float im = (slot == 2) ? 0.f : tileB[e * 5 + tau];
        x[q] = make_float2(re, im);
    }
    float2 b[16];
    fft1024_local(x, b, t, areas + tau * AREA);   // first barrier guards tiles
    int n1 = 4 * bx + tau;
    twiddle_L(b, n1, t);
    __syncthreads();
    // --- retranspose and write T[r*1024 + n1] ---
#pragma unroll
    for (int idx = 0; idx < 16; ++idx) {
        int c = idx >> 2, r4 = idx & 3;
        int r = t + 64 * c + 256 * r4;
        rtile[r * 5 + tau] = b[idx];
    }
    __syncthreads();
    float2* db = T + (size_t)slot * L_FFT;
#pragma unroll
    for (int it = 0; it < 4; ++it) {
        int row = tid + 256 * it;
        float2 v0 = rtile[row * 5 + 0], v1 = rtile[row * 5 + 1];
        float2 v2 = rtile[row * 5 + 2], v3 = rtile[row * 5 + 3];
        float4* d4 = (float4*)(db + (size_t)row * 1024 + 4 * bx);
        d4[0] = make_float4(v0.x, v0.y, v1.x, v1.y);
        d4[1] = make_float4(v2.x, v2.y, v3.x, v3.y);
    }
}

// ---- K2: forward pass 2 (final, trivial stage twiddle) + spectral multiply.
// Block b: line pair {b, 1024-b} (b=0: {0,512}, self-mirroring) for slots
// 0,1 and H (slot 2) concurrently: 6 transforms x 64 thr = 384 threads.
// Bins exchanged via LDS; writes conj(P) line-major (contiguous).
__global__ __launch_bounds__(384) void fwd2_spectral(const float2* __restrict__ T,
                                                     float2* __restrict__ Q) {
    __shared__ __align__(16) float2 areas[6 * AREA];
    int tid = threadIdx.x;
    int tau = tid >> 6, t = tid & 63;
    int s = tau >> 1, li = tau & 1;
    int blk = blockIdx.x;
    int line = (blk == 0) ? (li ? 512 : 0) : (li ? 1024 - blk : blk);

    const float2* sb = T + (size_t)s * L_FFT + (size_t)line * 1024;
    float2 x[16];
#pragma unroll
    for (int q = 0; q < 16; ++q) x[q] = sb[t + 64 * q];
    float2 b[16];
    float2* area = areas + tau * AREA;
    fft1024_local(x, b, t, area);
    __syncthreads();
    // publish bins X[k1] to own area
#pragma unroll
    for (int idx = 0; idx < 16; ++idx) {
        int c = idx >> 2, r4 = idx & 3;
        area[LP(t + 64 * c + 256 * r4)] = b[idx];
    }
    __syncthreads();
    if (s < 2) {
        const float2* Hrow = areas + (4 + li) * AREA;
        const float2* Prow = (blk == 0) ? area : (areas + (tau ^ 1) * AREA);
        float2* db = Q + (size_t)s * L_FFT + (size_t)line * 1024;
#pragma unroll
        for (int idx = 0; idx < 16; ++idx) {
            int c = idx >> 2, r4 = idx & 3;
            int k1 = t + 64 * c + 256 * r4;
            int mi = (blk == 0) ? ((line == 0) ? ((1024 - k1) & 1023) : (1023 - k1))
                                : (1023 - k1);
            float2 Z  = b[idx];
            float2 Zr = Prow[LP(mi)];
            float2 H  = Hrow[LP(k1)];
            float2 X0 = make_float2(0.5f * (Z.x + Zr.x), 0.5f * (Z.y - Zr.y));
            float2 X1 = make_float2(0.5f * (Z.y + Zr.y), 0.5f * (Zr.x - Z.x));
            float2 G0 = make_float2(X0.x * H.x + X0.y * H.y, X0.y * H.x - X0.x * H.y);
            float2 G1 = make_float2(X1.x * H.x + X1.y * H.y, X1.y * H.x - X1.x * H.y);
            db[k1] = make_float2(G0.x - G1.y, -(G0.y + G1.x));   // conj(P)
        }
    }
}

// ---- K4: inverse pass 1 (forward machinery on conj(P)). Digit-swapped
// storage makes the J=1 gather contiguous: natural element g+1024q lives at
// Q[g*1024 + q]. Twiddle w_L^{g*r}; transposed write A[r*1024 + g].
__global__ __launch_bounds__(256) void inv1(const float2* __restrict__ Q,
                                            float2* __restrict__ A) {
    __shared__ __align__(16) char smem[40960];
    float2* areas = (float2*)smem;
    float2* rtile = (float2*)smem;
    int tid = threadIdx.x;
    int bx = blockIdx.x, p = blockIdx.y;
    int tau = tid >> 6, t = tid & 63;
    int g = 4 * bx + tau;

    const float2* sb = Q + (size_t)p * L_FFT + (size_t)g * 1024;
    float2 x[16];
#pragma unroll
    for (int q = 0; q < 16; ++q) x[q] = sb[t + 64 * q];
    float2 b[16];
    fft1024_local(x, b, t, areas + tau * AREA);
    twiddle_L(b, g, t);
    __syncthreads();
#pragma unroll
    for (int idx = 0; idx < 16; ++idx) {
        int c = idx >> 2, r4 = idx & 3;
        rtile[(t + 64 * c + 256 * r4) * 5 + tau] = b[idx];
    }
    __syncthreads();
    float2* db = A + (size_t)p * L_FFT;
#pragma unroll
    for (int it = 0; it < 4; ++it) {
        int row = tid + 256 * it;
        float2 v0 = rtile[row * 5 + 0], v1 = rtile[row * 5 + 1];
        float2 v2 = rtile[row * 5 + 2], v3 = rtile[row * 5 + 3];
        float4* d4 = (float4*)(db + (size_t)row * 1024 + 4 * bx);
        d4[0] = make_float4(v0.x, v0.y, v1.x, v1.y);
        d4[1] = make_float4(v2.x, v2.y, v3.x, v3.y);
    }
}

// ---- K5: inverse pass 2 (final, trivial twiddle) + slice + max partials.
// Time index n = line + 1024*r. w = conj(q)/L: /L cancels, conj sign kept.
__global__ __launch_bounds__(256) void inv2_out(const float2* __restrict__ A,
                                                float* __restrict__ out,
                                                float* __restrict__ partials,
                                                int N, int V) {
    __shared__ __align__(16) char smem[40960];
    float2* areas = (float2*)smem;
    float2* rtile = (float2*)smem;
    int tid = threadIdx.x;
    int bx = blockIdx.x, p = blockIdx.y;
    int tau = tid >> 6, t = tid & 63;
    int line = 4 * bx + tau;

    const float2* sb = A + (size_t)p * L_FFT + (size_t)line * 1024;
    float2 x[16];
#pragma unroll
    for (int q = 0; q < 16; ++q) x[q] = sb[t + 64 * q];
    float2 b[16];
    fft1024_local(x, b, t, areas + tau * AREA);
    __syncthreads();
#pragma unroll
    for (int idx = 0; idx < 16; ++idx) {
        int c = idx >> 2, r4 = idx & 3;
        int r = t + 64 * c + 256 * r4;
        rtile[r * 5 + tau] = make_float2(b[idx].x, -b[idx].y);  // (Re, -Im)
    }
    __syncthreads();
    int se = 2 * p, so = 2 * p + 1;
    int lenO = (p == 1) ? (N - 3 * V) : V;
    float m = 0.f;
#pragma unroll
    for (int it = 0; it < 4; ++it) {
        int row = tid + 256 * it;
#pragma unroll
        for (int j = 0; j < 4; ++j) {
            int n = 4 * bx + j + 1024 * row;
            float2 v = rtile[row * 5 + j];
            if (n < V)    { out[(size_t)se * V + n] = v.x; m = fmaxf(m, fabsf(v.x)); }
            if (n < lenO) { out[(size_t)so * V + n] = v.y; m = fmaxf(m, fabsf(v.y)); }
        }
    }
    for (int o = 32; o > 0; o >>= 1) m = fmaxf(m, __shfl_xor(m, o));
    __shared__ float sm[4];
    int lane = tid & 63, wv = tid >> 6;
    if (lane == 0) sm[wv] = m;
    __syncthreads();
    if (tid == 0)
        partials[blockIdx.y * gridDim.x + blockIdx.x] =
            fmaxf(fmaxf(sm[0], sm[1]), fmaxf(sm[2], sm[3]));
}

// ---- K6: fused reduce + normalize (512 partials, no atomics).
__global__ void norm_fused(float* __restrict__ out,
                           const float* __restrict__ partials, int N) {
    float m = 0.f;
    for (int i = threadIdx.x; i < 512; i += 256) m = fmaxf(m, partials[i]);
    for (int o = 32; o > 0; o >>= 1) m = fmaxf(m, __shfl_xor(m, o));
    __shared__ float sm[4];
    int lane = threadIdx.x & 63, wv = threadIdx.x >> 6;
    if (lane == 0) sm[wv] = m;
    __syncthreads();
    float inv = 1.0f / fmaxf(fmaxf(sm[0], sm[1]), fmaxf(sm[2], sm[3]));
    int stride = gridDim.x * blockDim.x;
    for (int t = blockIdx.x * blockDim.x + threadIdx.x; t < N; t += stride)
        out[t] *= inv;
}

extern "C" void kernel_launch(void* const* d_in, const int* in_sizes, int n_in,
                              void* d_out, int out_size, void* d_ws, size_t ws_size,
                              hipStream_t stream) {
    const float* audio = (const float*)d_in[0];
    const float* ir    = (const float*)d_in[1];
    float* out = (float*)d_out;

    const int N = in_sizes[0];          // 2,646,000
    const int M = in_sizes[1];          // 220,500
    const int V = L_FFT - M + 1;        // 828,077

    float2* T = (float2*)d_ws;                       // 3L: pass-1 out (transposed)
    float2* Q = T + (size_t)3 * L_FFT;               // 2L: conj(P), line-major
    float* partials = (float*)(Q + (size_t)2 * L_FFT);

    fwd1_pack<<<dim3(256, 3), 256, 0, stream>>>(audio, ir, T, N, M, V);
    fwd2_spectral<<<512, 384, 0, stream>>>(T, Q);
    inv1<<<dim3(256, 2), 256, 0, stream>>>(Q, T);    // reuse T slots 0,1
    inv2_out<<<dim3(256, 2), 256, 0, stream>>>(T, out, partials, N, V);
    norm_fused<<<1024, 256, 0, stream>>>(out, partials, N);
}